// Round 7
// baseline (286.040 us; speedup 1.0000x reference)
//
#include <hip/hip_runtime.h>
#include <cstdint>
#include <cstddef>

// GCN 2-layer:
//   h   = relu(Agg(x@W1) + b1);  out = Agg(h@W2) + b2
//   Agg(z)[i] = dinv[i] * ( dinv[i]*z[i] + sum_{e: col(e)=i} dinv[row(e)]*z[row(e)] )
//   dinv[i] = rsqrt(1 + indeg(i))
// Factorization: xws = dinv ⊙ (A@W) (scaled in GEMM epilogue, bf16);
//   Agg reduces to out[i] = dinv[i]*(xws[i] + Σ_{nbr r} xws[r]) + b.
// GEMM on MFMA (bf16 in, fp32 acc), coalesced epilogue via LDS transpose.
// CSR built exactly each call (count -> scan -> fill) -> no uninit adj reads.
// Aggregate: quarter-wave (16 lanes) per node, uint4 (8 bf16)/lane, unroll-8;
// nodes processed in degree-sorted order (perm) so each wave's 4 chains have
// uniform degree -> minimal masked gather waste / max-of-4 divergence.

typedef unsigned int u32;
typedef unsigned short u16;
typedef __attribute__((ext_vector_type(8))) short short8;   // 8 bf16 (4 VGPRs)
typedef __attribute__((ext_vector_type(4))) float f32x4;    // MFMA acc

__device__ __forceinline__ float bf2f(u32 lo16) {
  union { u32 u; float f; } c; c.u = lo16 << 16; return c.f;
}
__device__ __forceinline__ u32 f2bf(float f) {  // round-to-nearest-even
  union { float f; u32 u; } c; c.f = f;
  return (c.u + 0x7fffu + ((c.u >> 16) & 1u)) >> 16;
}

__global__ __launch_bounds__(256) void zero_i32_kernel(int* __restrict__ p, int n) {
  int i = blockIdx.x * 256 + threadIdx.x;
  if (i < n) p[i] = 0;
}

__global__ __launch_bounds__(256) void count_kernel(
    const int* __restrict__ cols, const int* __restrict__ rows,
    int* __restrict__ cnt, int E, int N) {
  int e = blockIdx.x * 256 + threadIdx.x;
  if (e >= E) return;
  int c = cols[e];
  int r = rows[e];
  if ((unsigned)c >= (unsigned)N || (unsigned)r >= (unsigned)N) return;
  atomicAdd(&cnt[c], 1);
}

// W1,W2 [k][n] fp32 -> Wt1,Wt2 [n][k] bf16, one launch (128 blocks)
__global__ __launch_bounds__(256) void wt_kernel(
    const float* __restrict__ W1, const float* __restrict__ W2,
    u16* __restrict__ Wt1, u16* __restrict__ Wt2) {
  int b = blockIdx.x;
  const float* W = (b < 64) ? W1 : W2;
  u16* Wt = (b < 64) ? Wt1 : Wt2;
  int idx = (b & 63) * 256 + threadIdx.x;  // 0..16383
  int k = idx >> 7, n = idx & 127;
  Wt[n * 128 + k] = (u16)f2bf(W[idx]);
}

// ---- exclusive scan of cnt[N] -> rowptr[N]; also emits dinv (fused)
__global__ __launch_bounds__(256) void scan1_kernel(
    const int* __restrict__ cnt, int* __restrict__ rowptr,
    int* __restrict__ bsum, float* __restrict__ dinv, int N) {
  __shared__ int sd[256];
  int t = threadIdx.x;
  int base = blockIdx.x * 1024 + t * 4;
  int c0 = (base + 0 < N) ? cnt[base + 0] : 0;
  int c1 = (base + 1 < N) ? cnt[base + 1] : 0;
  int c2 = (base + 2 < N) ? cnt[base + 2] : 0;
  int c3 = (base + 3 < N) ? cnt[base + 3] : 0;
  if (base + 0 < N) dinv[base + 0] = rsqrtf((float)c0 + 1.0f);
  if (base + 1 < N) dinv[base + 1] = rsqrtf((float)c1 + 1.0f);
  if (base + 2 < N) dinv[base + 2] = rsqrtf((float)c2 + 1.0f);
  if (base + 3 < N) dinv[base + 3] = rsqrtf((float)c3 + 1.0f);
  int s = c0 + c1 + c2 + c3;
  sd[t] = s;
  __syncthreads();
  for (int off = 1; off < 256; off <<= 1) {
    int v = (t >= off) ? sd[t - off] : 0;
    __syncthreads();
    sd[t] += v;
    __syncthreads();
  }
  int excl = sd[t] - s;
  if (base + 0 < N) rowptr[base + 0] = excl;
  if (base + 1 < N) rowptr[base + 1] = excl + c0;
  if (base + 2 < N) rowptr[base + 2] = excl + c0 + c1;
  if (base + 3 < N) rowptr[base + 3] = excl + c0 + c1 + c2;
  if (t == 255) bsum[blockIdx.x] = sd[255];
}

// also zeroes the 32-bin degree histogram (used later by hist_kernel)
__global__ __launch_bounds__(128) void scan2_kernel(
    const int* __restrict__ bsum, int* __restrict__ bsum2,
    int* __restrict__ rowptr, int* __restrict__ hist, int NB, int N) {
  __shared__ int sd[128];
  int t = threadIdx.x;
  if (t < 32) hist[t] = 0;
  int v = (t < NB) ? bsum[t] : 0;
  sd[t] = v;
  __syncthreads();
  for (int off = 1; off < 128; off <<= 1) {
    int u = (t >= off) ? sd[t - off] : 0;
    __syncthreads();
    sd[t] += u;
    __syncthreads();
  }
  bsum2[t] = sd[t] - v;
  if (t == NB - 1) rowptr[N] = sd[t];
}

__global__ __launch_bounds__(256) void scan3_kernel(
    int* __restrict__ rowptr, const int* __restrict__ bsum2, int N) {
  int t = threadIdx.x;
  int b = blockIdx.x;
  int base = b * 1024 + t * 4;
  int add = bsum2[b];
#pragma unroll
  for (int k = 0; k < 4; k++)
    if (base + k < N) rowptr[base + k] += add;
}

// cnt doubles as the cursor: atomicSub returns old count, pos = old-1 in [0,deg)
__global__ __launch_bounds__(256) void fill_kernel(
    const int* __restrict__ cols, const int* __restrict__ rows,
    const int* __restrict__ rowptr, int* __restrict__ cnt,
    int* __restrict__ adj, int E, int N) {
  int e = blockIdx.x * 256 + threadIdx.x;
  if (e >= E) return;
  int c = cols[e];
  int r = rows[e];
  if ((unsigned)c >= (unsigned)N || (unsigned)r >= (unsigned)N) return;
  int pos = atomicSub(&cnt[c], 1) - 1;
  if (pos >= 0) adj[rowptr[c] + pos] = r;
}

// degree histogram (32 bins, bin = min(deg,31)); two-level to avoid hot atomics
__global__ __launch_bounds__(256) void hist_kernel(
    const int* __restrict__ rowptr, int* __restrict__ hist, int N) {
  __shared__ int lh[32];
  int t = threadIdx.x;
  if (t < 32) lh[t] = 0;
  __syncthreads();
  int i = blockIdx.x * 256 + t;
  if (i < N) {
    int deg = rowptr[i + 1] - rowptr[i];
    int bin = deg < 31 ? deg : 31;
    atomicAdd(&lh[bin], 1);
  }
  __syncthreads();
  if (t < 32 && lh[t] > 0) atomicAdd(&hist[t], lh[t]);
}

// exclusive prefix of hist -> bincur (32 entries; trivial single-thread scan)
__global__ __launch_bounds__(64) void binscan_kernel(
    const int* __restrict__ hist, int* __restrict__ bincur) {
  if (threadIdx.x == 0) {
    int acc = 0;
    for (int b = 0; b < 32; b++) { bincur[b] = acc; acc += hist[b]; }
  }
}

// counting-sort scatter: perm gets node ids grouped by degree bin.
// two-level: LDS local histogram -> one global atomicAdd per bin per block.
__global__ __launch_bounds__(256) void perm_kernel(
    const int* __restrict__ rowptr, int* __restrict__ bincur,
    int* __restrict__ perm, int N) {
  __shared__ int lh[32];
  __shared__ int lbase[32];
  int t = threadIdx.x;
  if (t < 32) lh[t] = 0;
  __syncthreads();
  int i = blockIdx.x * 256 + t;
  int bin = 0, lpos = 0;
  if (i < N) {
    int deg = rowptr[i + 1] - rowptr[i];
    bin = deg < 31 ? deg : 31;
    lpos = atomicAdd(&lh[bin], 1);
  }
  __syncthreads();
  if (t < 32) lbase[t] = (lh[t] > 0) ? atomicAdd(&bincur[t], lh[t]) : 0;
  __syncthreads();
  if (i < N) perm[lbase[bin] + lpos] = i;
}

// C_bf16[M,128] = dinv[row] * (A[M,128] @ W[128,128]) via MFMA 16x16x32 bf16.
// Block = 256 thr (4 waves), tile 128 rows; wave w owns rows w*32..+31
// (2 m-tiles) x 128 cols (8 n-tiles). Wt staged once in LDS [n][k] pad 136.
// A fragments straight from global (each byte read once; no k-loop barrier).
// Epilogue: scaled bf16 tile round-trips through Ws (dead after k-loop) so
// global stores are coalesced uint4.
// Fragment layouts (m89/m118-verified):
//   A: lane holds A[m=lane&15][k=quad*8+j];  B: B[k=quad*8+j][n=lane&15]
//   C/D: col=lane&15, row=quad*4+reg
template <int A_BF16>
__global__ __launch_bounds__(256) void gemm_mfma_kernel(
    const void* __restrict__ Av, const u16* __restrict__ Wt,
    const float* __restrict__ dinv, u16* __restrict__ C, int M) {
  __shared__ u16 Ws[128][136];
  __shared__ float dv_s[128];
  const int tid = threadIdx.x;
  const int row0 = blockIdx.x * 128;

  {
    const uint4* src = (const uint4*)Wt;  // 2048 x 16B
#pragma unroll
    for (int i = 0; i < 8; i++) {
      int linear = tid + i * 256;
      int n = linear >> 4;
      int kq = linear & 15;
      *(uint4*)&Ws[n][kq * 8] = src[linear];
    }
  }
  if (tid < 128) {
    int gr = row0 + tid;
    dv_s[tid] = (gr < M) ? dinv[gr] : 0.f;
  }
  __syncthreads();

  const int wave = tid >> 6;
  const int lane = tid & 63;
  const int lm = lane & 15;
  const int quad = lane >> 4;
  const int m0 = wave * 32;

  f32x4 acc[2][8];
#pragma unroll
  for (int mt = 0; mt < 2; mt++)
#pragma unroll
    for (int nt = 0; nt < 8; nt++) acc[mt][nt] = (f32x4){0.f, 0.f, 0.f, 0.f};

#pragma unroll
  for (int k0 = 0; k0 < 128; k0 += 32) {
    short8 bfrag[8];
#pragma unroll
    for (int nt = 0; nt < 8; nt++)
      bfrag[nt] = *(const short8*)&Ws[nt * 16 + lm][k0 + quad * 8];

    short8 afrag[2];
#pragma unroll
    for (int mt = 0; mt < 2; mt++) {
      int gr = row0 + m0 + mt * 16 + lm;
      short8 f = (short8){0, 0, 0, 0, 0, 0, 0, 0};
      if (gr < M) {
        if (A_BF16) {
          f = *(const short8*)((const u16*)Av + (size_t)gr * 128 + k0 + quad * 8);
        } else {
          const float* Af = (const float*)Av + (size_t)gr * 128 + k0 + quad * 8;
          float4 v0 = *(const float4*)Af;
          float4 v1 = *(const float4*)(Af + 4);
          f[0] = (short)f2bf(v0.x); f[1] = (short)f2bf(v0.y);
          f[2] = (short)f2bf(v0.z); f[3] = (short)f2bf(v0.w);
          f[4] = (short)f2bf(v1.x); f[5] = (short)f2bf(v1.y);
          f[6] = (short)f2bf(v1.z); f[7] = (short)f2bf(v1.w);
        }
      }
      afrag[mt] = f;
    }

#pragma unroll
    for (int mt = 0; mt < 2; mt++)
#pragma unroll
      for (int nt = 0; nt < 8; nt++)
        acc[mt][nt] = __builtin_amdgcn_mfma_f32_16x16x32_bf16(
            afrag[mt], bfrag[nt], acc[mt][nt], 0, 0, 0);
  }

  // epilogue: scale by dinv[row], pack bf16 into Ws (dead), store coalesced
  __syncthreads();  // all waves done reading Ws
#pragma unroll
  for (int mt = 0; mt < 2; mt++) {
    int rbase = m0 + mt * 16 + quad * 4;
#pragma unroll
    for (int r = 0; r < 4; r++) {
      int lrow = rbase + r;
      float dv = dv_s[lrow];
#pragma unroll
      for (int nt = 0; nt < 8; nt++)
        Ws[lrow][nt * 16 + lm] = (u16)f2bf(acc[mt][nt][r] * dv);
    }
  }
  __syncthreads();
#pragma unroll
  for (int i = 0; i < 8; i++) {
    int linear = tid + i * 256;  // 0..2047
    int row = linear >> 4;
    int c8 = linear & 15;        // 8-col chunk
    int grow = row0 + row;
    if (grow < M)
      *(uint4*)(C + (size_t)grow * 128 + c8 * 8) = *(const uint4*)&Ws[row][c8 * 8];
  }
}

// Quarter-wave (16 lanes) per node; lane owns cols 8l..8l+7 (uint4 = 8 bf16).
// Nodes taken in degree-sorted order via perm -> uniform chains per wave.
template <int RELU, int OUT_BF16>
__global__ __launch_bounds__(256) void aggregate_kernel(
    const uint4* __restrict__ xws, const int* __restrict__ rowptr,
    const int* __restrict__ adj, const float* __restrict__ dinv,
    const float* __restrict__ bias, const int* __restrict__ perm,
    void* __restrict__ out, int N) {
  int idx = blockIdx.x * 16 + (threadIdx.x >> 4);
  if (idx >= N) return;
  int node = perm[idx];
  if ((unsigned)node >= (unsigned)N) node = 0;  // poison guard
  int lane = threadIdx.x & 15;

  float a[8];
  {
    uint4 sv = xws[(size_t)node * 16 + lane];
    a[0] = bf2f(sv.x & 0xffff); a[1] = bf2f(sv.x >> 16);
    a[2] = bf2f(sv.y & 0xffff); a[3] = bf2f(sv.y >> 16);
    a[4] = bf2f(sv.z & 0xffff); a[5] = bf2f(sv.z >> 16);
    a[6] = bf2f(sv.w & 0xffff); a[7] = bf2f(sv.w >> 16);
  }

  int beg = rowptr[node];
  int end = rowptr[node + 1];
  for (int j = beg; j < end; j += 8) {
    int sidx[8];
    float msk[8];
#pragma unroll
    for (int k = 0; k < 8; k++) {
      int jj = j + k;
      int s = (jj < end) ? adj[jj] : -1;
      float m = 1.f;
      if ((unsigned)s >= (unsigned)N) { s = 0; m = 0.f; }
      sidx[k] = s;
      msk[k] = m;
    }
    uint4 v[8];
#pragma unroll
    for (int k = 0; k < 8; k++) v[k] = xws[(size_t)sidx[k] * 16 + lane];
#pragma unroll
    for (int k = 0; k < 8; k++) {
      a[0] = fmaf(msk[k], bf2f(v[k].x & 0xffff), a[0]);
      a[1] = fmaf(msk[k], bf2f(v[k].x >> 16), a[1]);
      a[2] = fmaf(msk[k], bf2f(v[k].y & 0xffff), a[2]);
      a[3] = fmaf(msk[k], bf2f(v[k].y >> 16), a[3]);
      a[4] = fmaf(msk[k], bf2f(v[k].z & 0xffff), a[4]);
      a[5] = fmaf(msk[k], bf2f(v[k].z >> 16), a[5]);
      a[6] = fmaf(msk[k], bf2f(v[k].w & 0xffff), a[6]);
      a[7] = fmaf(msk[k], bf2f(v[k].w >> 16), a[7]);
    }
  }

  float di = dinv[node];
  float4 b0 = ((const float4*)bias)[lane * 2];
  float4 b1 = ((const float4*)bias)[lane * 2 + 1];
  float o[8];
  o[0] = fmaf(di, a[0], b0.x); o[1] = fmaf(di, a[1], b0.y);
  o[2] = fmaf(di, a[2], b0.z); o[3] = fmaf(di, a[3], b0.w);
  o[4] = fmaf(di, a[4], b1.x); o[5] = fmaf(di, a[5], b1.y);
  o[6] = fmaf(di, a[6], b1.z); o[7] = fmaf(di, a[7], b1.w);
  if (RELU) {
#pragma unroll
    for (int k = 0; k < 8; k++) o[k] = fmaxf(o[k], 0.f);
  }
  if (OUT_BF16) {
    uint4 p;
    p.x = f2bf(o[0]) | (f2bf(o[1]) << 16);
    p.y = f2bf(o[2]) | (f2bf(o[3]) << 16);
    p.z = f2bf(o[4]) | (f2bf(o[5]) << 16);
    p.w = f2bf(o[6]) | (f2bf(o[7]) << 16);
    ((uint4*)out)[(size_t)node * 16 + lane] = p;
  } else {
    float4* op = (float4*)out + (size_t)node * 32 + lane * 2;
    op[0] = make_float4(o[0], o[1], o[2], o[3]);
    op[1] = make_float4(o[4], o[5], o[6], o[7]);
  }
}

extern "C" void kernel_launch(void* const* d_in, const int* in_sizes, int n_in,
                              void* d_out, int out_size, void* d_ws, size_t ws_size,
                              hipStream_t stream) {
  const float* x  = (const float*)d_in[0];
  const int*   ei = (const int*)d_in[1];
  const float* W1 = (const float*)d_in[2];
  const float* b1 = (const float*)d_in[3];
  const float* W2 = (const float*)d_in[4];
  const float* b2 = (const float*)d_in[5];
  float* out = (float*)d_out;

  const int F = 128;
  const int N = in_sizes[0] / F;
  const int E = in_sizes[1] / 2;
  const int* rows = ei;       // edge_index[0] = source
  const int* cols = ei + E;   // edge_index[1] = destination

  // workspace layout (~57 MB)
  u16*   bufXW  = (u16*)d_ws;                      // N*128 bf16 (xws scratch)
  u16*   bufH   = bufXW + (size_t)N * F;           // N*128 bf16 (h)
  float* dinv   = (float*)(bufH + (size_t)N * F);  // N f32
  int*   cnt    = (int*)(dinv + N);                // N i32 (count, then cursor)
  int*   rowptr = cnt + N;                         // N+1 i32
  int*   adj    = rowptr + (N + 1);                // E i32
  int*   bsum   = adj + E;                         // 128 i32
  int*   bsum2  = bsum + 128;                      // 128 i32
  int*   hist   = bsum2 + 128;                     // 32 i32
  int*   bincur = hist + 32;                       // 32 i32
  int*   perm   = bincur + 32;                     // N i32
  u16*   Wt1    = (u16*)(perm + N);                // 128*128 bf16 (W1^T)
  u16*   Wt2    = Wt1 + 128 * 128;                 // 128*128 bf16 (W2^T)

  const int NB = (N + 1023) / 1024;
  int eblocks = (E + 255) / 256;
  int nblocks = (N + 255) / 256;

  // build exact CSR + dinv + degree-sorted perm; transpose/convert weights
  zero_i32_kernel<<<nblocks, 256, 0, stream>>>(cnt, N);
  count_kernel<<<eblocks, 256, 0, stream>>>(cols, rows, cnt, E, N);
  wt_kernel<<<128, 256, 0, stream>>>(W1, W2, Wt1, Wt2);
  scan1_kernel<<<NB, 256, 0, stream>>>(cnt, rowptr, bsum, dinv, N);
  scan2_kernel<<<1, 128, 0, stream>>>(bsum, bsum2, rowptr, hist, NB, N);
  scan3_kernel<<<NB, 256, 0, stream>>>(rowptr, bsum2, N);
  fill_kernel<<<eblocks, 256, 0, stream>>>(cols, rows, rowptr, cnt, adj, E, N);
  hist_kernel<<<nblocks, 256, 0, stream>>>(rowptr, hist, N);
  binscan_kernel<<<1, 64, 0, stream>>>(hist, bincur);
  perm_kernel<<<nblocks, 256, 0, stream>>>(rowptr, bincur, perm, N);

  int gblocks = (N + 127) / 128;
  int ablocks = (N + 15) / 16;
  // layer 1: xws1 = dinv ⊙ (x@W1) (bf16) ; h = relu(dinv⊙Σ + b1) -> bufH (bf16)
  gemm_mfma_kernel<0><<<gblocks, 256, 0, stream>>>(x, Wt1, dinv, bufXW, N);
  aggregate_kernel<1, 1><<<ablocks, 256, 0, stream>>>(
      (const uint4*)bufXW, rowptr, adj, dinv, b1, perm, bufH, N);
  // layer 2: xws2 = dinv ⊙ (h@W2) (bf16) ; out = dinv⊙Σ + b2 -> d_out (fp32)
  gemm_mfma_kernel<1><<<gblocks, 256, 0, stream>>>(bufH, Wt2, dinv, bufXW, N);
  aggregate_kernel<0, 0><<<ablocks, 256, 0, stream>>>(
      (const uint4*)bufXW, rowptr, adj, dinv, b2, perm, out, N);
}

// Round 8
// 263.444 us; speedup vs baseline: 1.0858x; 1.0858x over previous
//
#include <hip/hip_runtime.h>
#include <cstdint>
#include <cstddef>

// GCN 2-layer:
//   h   = relu(Agg(x@W1) + b1);  out = Agg(h@W2) + b2
//   Agg(z)[i] = dinv[i] * ( dinv[i]*z[i] + sum_{e: col(e)=i} dinv[row(e)]*z[row(e)] )
//   dinv[i] = rsqrt(1 + indeg(i))
// Factorization: xws = dinv ⊙ (A@W) (scaled in GEMM epilogue, bf16);
//   Agg reduces to out[i] = dinv[i]*(xws[i] + Σ_{nbr r} xws[r]) + b.
// GEMM on MFMA (bf16 in, fp32 acc), coalesced epilogue via LDS transpose.
// CSR built exactly each call (count -> scan -> fill) -> no uninit adj reads.
// count/fill: 4 independent edge-chains per thread (latency-bound atomics).
// Aggregate: quarter-wave (16 lanes) per node, uint4 (8 bf16)/lane, unroll-8.

typedef unsigned int u32;
typedef unsigned short u16;
typedef __attribute__((ext_vector_type(8))) short short8;   // 8 bf16 (4 VGPRs)
typedef __attribute__((ext_vector_type(4))) float f32x4;    // MFMA acc

__device__ __forceinline__ float bf2f(u32 lo16) {
  union { u32 u; float f; } c; c.u = lo16 << 16; return c.f;
}
__device__ __forceinline__ u32 f2bf(float f) {  // round-to-nearest-even
  union { float f; u32 u; } c; c.f = f;
  return (c.u + 0x7fffu + ((c.u >> 16) & 1u)) >> 16;
}

__global__ __launch_bounds__(256) void zero_i32_kernel(int* __restrict__ p, int n) {
  int i = blockIdx.x * 256 + threadIdx.x;
  if (i < n) p[i] = 0;
}

// 4 edges per thread, grid-strided for coalesced index loads; 4 independent
// atomic chains per thread to hide L2/L3 atomic latency.
__global__ __launch_bounds__(256) void count_kernel(
    const int* __restrict__ cols, int* __restrict__ cnt, int E, int N) {
  int t = blockIdx.x * 256 + threadIdx.x;
  int T = gridDim.x * 256;
#pragma unroll
  for (int k = 0; k < 4; k++) {
    int e = t + k * T;
    if (e < E) {
      int c = cols[e];
      if ((unsigned)c < (unsigned)N) atomicAdd(&cnt[c], 1);
    }
  }
}

// W1,W2 [k][n] fp32 -> Wt1,Wt2 [n][k] bf16, one launch (128 blocks)
__global__ __launch_bounds__(256) void wt_kernel(
    const float* __restrict__ W1, const float* __restrict__ W2,
    u16* __restrict__ Wt1, u16* __restrict__ Wt2) {
  int b = blockIdx.x;
  const float* W = (b < 64) ? W1 : W2;
  u16* Wt = (b < 64) ? Wt1 : Wt2;
  int idx = (b & 63) * 256 + threadIdx.x;  // 0..16383
  int k = idx >> 7, n = idx & 127;
  Wt[n * 128 + k] = (u16)f2bf(W[idx]);
}

// ---- exclusive scan of cnt[N] -> rowptr[N]; also emits dinv (fused)
__global__ __launch_bounds__(256) void scan1_kernel(
    const int* __restrict__ cnt, int* __restrict__ rowptr,
    int* __restrict__ bsum, float* __restrict__ dinv, int N) {
  __shared__ int sd[256];
  int t = threadIdx.x;
  int base = blockIdx.x * 1024 + t * 4;
  int c0 = (base + 0 < N) ? cnt[base + 0] : 0;
  int c1 = (base + 1 < N) ? cnt[base + 1] : 0;
  int c2 = (base + 2 < N) ? cnt[base + 2] : 0;
  int c3 = (base + 3 < N) ? cnt[base + 3] : 0;
  if (base + 0 < N) dinv[base + 0] = rsqrtf((float)c0 + 1.0f);
  if (base + 1 < N) dinv[base + 1] = rsqrtf((float)c1 + 1.0f);
  if (base + 2 < N) dinv[base + 2] = rsqrtf((float)c2 + 1.0f);
  if (base + 3 < N) dinv[base + 3] = rsqrtf((float)c3 + 1.0f);
  int s = c0 + c1 + c2 + c3;
  sd[t] = s;
  __syncthreads();
  for (int off = 1; off < 256; off <<= 1) {
    int v = (t >= off) ? sd[t - off] : 0;
    __syncthreads();
    sd[t] += v;
    __syncthreads();
  }
  int excl = sd[t] - s;
  if (base + 0 < N) rowptr[base + 0] = excl;
  if (base + 1 < N) rowptr[base + 1] = excl + c0;
  if (base + 2 < N) rowptr[base + 2] = excl + c0 + c1;
  if (base + 3 < N) rowptr[base + 3] = excl + c0 + c1 + c2;
  if (t == 255) bsum[blockIdx.x] = sd[255];
}

__global__ __launch_bounds__(128) void scan2_kernel(
    const int* __restrict__ bsum, int* __restrict__ bsum2,
    int* __restrict__ rowptr, int NB, int N) {
  __shared__ int sd[128];
  int t = threadIdx.x;
  int v = (t < NB) ? bsum[t] : 0;
  sd[t] = v;
  __syncthreads();
  for (int off = 1; off < 128; off <<= 1) {
    int u = (t >= off) ? sd[t - off] : 0;
    __syncthreads();
    sd[t] += u;
    __syncthreads();
  }
  bsum2[t] = sd[t] - v;
  if (t == NB - 1) rowptr[N] = sd[t];
}

__global__ __launch_bounds__(256) void scan3_kernel(
    int* __restrict__ rowptr, const int* __restrict__ bsum2, int N) {
  int t = threadIdx.x;
  int b = blockIdx.x;
  int base = b * 1024 + t * 4;
  int add = bsum2[b];
#pragma unroll
  for (int k = 0; k < 4; k++)
    if (base + k < N) rowptr[base + k] += add;
}

// cnt doubles as cursor: atomicSub returns old count, pos = old-1 in [0,deg).
// 4 edges/thread, grid-strided; rowptr prefetched for all 4 before atomics so
// the (load -> atomic -> store) chains overlap.
__global__ __launch_bounds__(256) void fill_kernel(
    const int* __restrict__ cols, const int* __restrict__ rows,
    const int* __restrict__ rowptr, int* __restrict__ cnt,
    int* __restrict__ adj, int E, int N) {
  int t = blockIdx.x * 256 + threadIdx.x;
  int T = gridDim.x * 256;
  int c[4], r[4], rp[4];
  bool ok[4];
#pragma unroll
  for (int k = 0; k < 4; k++) {
    int e = t + k * T;
    ok[k] = false;
    c[k] = 0; r[k] = 0;
    if (e < E) {
      c[k] = cols[e];
      r[k] = rows[e];
      ok[k] = ((unsigned)c[k] < (unsigned)N) && ((unsigned)r[k] < (unsigned)N);
      if (!ok[k]) c[k] = 0;
    }
  }
#pragma unroll
  for (int k = 0; k < 4; k++) rp[k] = rowptr[c[k]];  // independent prefetch
#pragma unroll
  for (int k = 0; k < 4; k++) {
    if (ok[k]) {
      int pos = atomicSub(&cnt[c[k]], 1) - 1;
      if (pos >= 0) adj[rp[k] + pos] = r[k];
    }
  }
}

// C_bf16[M,128] = dinv[row] * (A[M,128] @ W[128,128]) via MFMA 16x16x32 bf16.
// Block = 256 thr (4 waves), tile 128 rows; wave w owns rows w*32..+31
// (2 m-tiles) x 128 cols (8 n-tiles). Wt staged once in LDS [n][k] pad 136.
// A fragments straight from global (each byte read once; no k-loop barrier).
// Epilogue: scaled bf16 tile round-trips through Ws (dead after k-loop) so
// global stores are coalesced uint4.
// Fragment layouts (m89/m118-verified):
//   A: lane holds A[m=lane&15][k=quad*8+j];  B: B[k=quad*8+j][n=lane&15]
//   C/D: col=lane&15, row=quad*4+reg
template <int A_BF16>
__global__ __launch_bounds__(256) void gemm_mfma_kernel(
    const void* __restrict__ Av, const u16* __restrict__ Wt,
    const float* __restrict__ dinv, u16* __restrict__ C, int M) {
  __shared__ u16 Ws[128][136];
  __shared__ float dv_s[128];
  const int tid = threadIdx.x;
  const int row0 = blockIdx.x * 128;

  {
    const uint4* src = (const uint4*)Wt;  // 2048 x 16B
#pragma unroll
    for (int i = 0; i < 8; i++) {
      int linear = tid + i * 256;
      int n = linear >> 4;
      int kq = linear & 15;
      *(uint4*)&Ws[n][kq * 8] = src[linear];
    }
  }
  if (tid < 128) {
    int gr = row0 + tid;
    dv_s[tid] = (gr < M) ? dinv[gr] : 0.f;
  }
  __syncthreads();

  const int wave = tid >> 6;
  const int lane = tid & 63;
  const int lm = lane & 15;
  const int quad = lane >> 4;
  const int m0 = wave * 32;

  f32x4 acc[2][8];
#pragma unroll
  for (int mt = 0; mt < 2; mt++)
#pragma unroll
    for (int nt = 0; nt < 8; nt++) acc[mt][nt] = (f32x4){0.f, 0.f, 0.f, 0.f};

#pragma unroll
  for (int k0 = 0; k0 < 128; k0 += 32) {
    short8 bfrag[8];
#pragma unroll
    for (int nt = 0; nt < 8; nt++)
      bfrag[nt] = *(const short8*)&Ws[nt * 16 + lm][k0 + quad * 8];

    short8 afrag[2];
#pragma unroll
    for (int mt = 0; mt < 2; mt++) {
      int gr = row0 + m0 + mt * 16 + lm;
      short8 f = (short8){0, 0, 0, 0, 0, 0, 0, 0};
      if (gr < M) {
        if (A_BF16) {
          f = *(const short8*)((const u16*)Av + (size_t)gr * 128 + k0 + quad * 8);
        } else {
          const float* Af = (const float*)Av + (size_t)gr * 128 + k0 + quad * 8;
          float4 v0 = *(const float4*)Af;
          float4 v1 = *(const float4*)(Af + 4);
          f[0] = (short)f2bf(v0.x); f[1] = (short)f2bf(v0.y);
          f[2] = (short)f2bf(v0.z); f[3] = (short)f2bf(v0.w);
          f[4] = (short)f2bf(v1.x); f[5] = (short)f2bf(v1.y);
          f[6] = (short)f2bf(v1.z); f[7] = (short)f2bf(v1.w);
        }
      }
      afrag[mt] = f;
    }

#pragma unroll
    for (int mt = 0; mt < 2; mt++)
#pragma unroll
      for (int nt = 0; nt < 8; nt++)
        acc[mt][nt] = __builtin_amdgcn_mfma_f32_16x16x32_bf16(
            afrag[mt], bfrag[nt], acc[mt][nt], 0, 0, 0);
  }

  // epilogue: scale by dinv[row], pack bf16 into Ws (dead), store coalesced
  __syncthreads();  // all waves done reading Ws
#pragma unroll
  for (int mt = 0; mt < 2; mt++) {
    int rbase = m0 + mt * 16 + quad * 4;
#pragma unroll
    for (int r = 0; r < 4; r++) {
      int lrow = rbase + r;
      float dv = dv_s[lrow];
#pragma unroll
      for (int nt = 0; nt < 8; nt++)
        Ws[lrow][nt * 16 + lm] = (u16)f2bf(acc[mt][nt][r] * dv);
    }
  }
  __syncthreads();
#pragma unroll
  for (int i = 0; i < 8; i++) {
    int linear = tid + i * 256;  // 0..2047
    int row = linear >> 4;
    int c8 = linear & 15;        // 8-col chunk
    int grow = row0 + row;
    if (grow < M)
      *(uint4*)(C + (size_t)grow * 128 + c8 * 8) = *(const uint4*)&Ws[row][c8 * 8];
  }
}

// Quarter-wave (16 lanes) per node; lane owns cols 8l..8l+7 (uint4 = 8 bf16).
// 4 independent node chains per wave + unroll-8 -> 32 outstanding 16B gathers.
template <int RELU, int OUT_BF16>
__global__ __launch_bounds__(256) void aggregate_kernel(
    const uint4* __restrict__ xws, const int* __restrict__ rowptr,
    const int* __restrict__ adj, const float* __restrict__ dinv,
    const float* __restrict__ bias, void* __restrict__ out, int N) {
  int node = blockIdx.x * 16 + (threadIdx.x >> 4);
  if (node >= N) return;
  int lane = threadIdx.x & 15;

  float a[8];
  {
    uint4 sv = xws[(size_t)node * 16 + lane];
    a[0] = bf2f(sv.x & 0xffff); a[1] = bf2f(sv.x >> 16);
    a[2] = bf2f(sv.y & 0xffff); a[3] = bf2f(sv.y >> 16);
    a[4] = bf2f(sv.z & 0xffff); a[5] = bf2f(sv.z >> 16);
    a[6] = bf2f(sv.w & 0xffff); a[7] = bf2f(sv.w >> 16);
  }

  int beg = rowptr[node];
  int end = rowptr[node + 1];
  for (int j = beg; j < end; j += 8) {
    int sidx[8];
    float msk[8];
#pragma unroll
    for (int k = 0; k < 8; k++) {
      int jj = j + k;
      int s = (jj < end) ? adj[jj] : -1;
      float m = 1.f;
      if ((unsigned)s >= (unsigned)N) { s = 0; m = 0.f; }
      sidx[k] = s;
      msk[k] = m;
    }
    uint4 v[8];
#pragma unroll
    for (int k = 0; k < 8; k++) v[k] = xws[(size_t)sidx[k] * 16 + lane];
#pragma unroll
    for (int k = 0; k < 8; k++) {
      a[0] = fmaf(msk[k], bf2f(v[k].x & 0xffff), a[0]);
      a[1] = fmaf(msk[k], bf2f(v[k].x >> 16), a[1]);
      a[2] = fmaf(msk[k], bf2f(v[k].y & 0xffff), a[2]);
      a[3] = fmaf(msk[k], bf2f(v[k].y >> 16), a[3]);
      a[4] = fmaf(msk[k], bf2f(v[k].z & 0xffff), a[4]);
      a[5] = fmaf(msk[k], bf2f(v[k].z >> 16), a[5]);
      a[6] = fmaf(msk[k], bf2f(v[k].w & 0xffff), a[6]);
      a[7] = fmaf(msk[k], bf2f(v[k].w >> 16), a[7]);
    }
  }

  float di = dinv[node];
  float4 b0 = ((const float4*)bias)[lane * 2];
  float4 b1 = ((const float4*)bias)[lane * 2 + 1];
  float o[8];
  o[0] = fmaf(di, a[0], b0.x); o[1] = fmaf(di, a[1], b0.y);
  o[2] = fmaf(di, a[2], b0.z); o[3] = fmaf(di, a[3], b0.w);
  o[4] = fmaf(di, a[4], b1.x); o[5] = fmaf(di, a[5], b1.y);
  o[6] = fmaf(di, a[6], b1.z); o[7] = fmaf(di, a[7], b1.w);
  if (RELU) {
#pragma unroll
    for (int k = 0; k < 8; k++) o[k] = fmaxf(o[k], 0.f);
  }
  if (OUT_BF16) {
    uint4 p;
    p.x = f2bf(o[0]) | (f2bf(o[1]) << 16);
    p.y = f2bf(o[2]) | (f2bf(o[3]) << 16);
    p.z = f2bf(o[4]) | (f2bf(o[5]) << 16);
    p.w = f2bf(o[6]) | (f2bf(o[7]) << 16);
    ((uint4*)out)[(size_t)node * 16 + lane] = p;
  } else {
    float4* op = (float4*)out + (size_t)node * 32 + lane * 2;
    op[0] = make_float4(o[0], o[1], o[2], o[3]);
    op[1] = make_float4(o[4], o[5], o[6], o[7]);
  }
}

extern "C" void kernel_launch(void* const* d_in, const int* in_sizes, int n_in,
                              void* d_out, int out_size, void* d_ws, size_t ws_size,
                              hipStream_t stream) {
  const float* x  = (const float*)d_in[0];
  const int*   ei = (const int*)d_in[1];
  const float* W1 = (const float*)d_in[2];
  const float* b1 = (const float*)d_in[3];
  const float* W2 = (const float*)d_in[4];
  const float* b2 = (const float*)d_in[5];
  float* out = (float*)d_out;

  const int F = 128;
  const int N = in_sizes[0] / F;
  const int E = in_sizes[1] / 2;
  const int* rows = ei;       // edge_index[0] = source
  const int* cols = ei + E;   // edge_index[1] = destination

  // workspace layout (~55 MB)
  u16*   bufXW  = (u16*)d_ws;                      // N*128 bf16 (xws scratch)
  u16*   bufH   = bufXW + (size_t)N * F;           // N*128 bf16 (h)
  float* dinv   = (float*)(bufH + (size_t)N * F);  // N f32
  int*   cnt    = (int*)(dinv + N);                // N i32 (count, then cursor)
  int*   rowptr = cnt + N;                         // N+1 i32
  int*   adj    = rowptr + (N + 1);                // E i32
  int*   bsum   = adj + E;                         // 128 i32
  int*   bsum2  = bsum + 128;                      // 128 i32
  u16*   Wt1    = (u16*)(bsum2 + 128);             // 128*128 bf16 (W1^T)
  u16*   Wt2    = Wt1 + 128 * 128;                 // 128*128 bf16 (W2^T)

  const int NB = (N + 1023) / 1024;
  int nblocks = (N + 255) / 256;
  int e4blocks = ((E + 3) / 4 + 255) / 256;  // 4 edges per thread

  // build exact CSR + dinv; transpose/convert weights
  zero_i32_kernel<<<nblocks, 256, 0, stream>>>(cnt, N);
  count_kernel<<<e4blocks, 256, 0, stream>>>(cols, cnt, E, N);
  wt_kernel<<<128, 256, 0, stream>>>(W1, W2, Wt1, Wt2);
  scan1_kernel<<<NB, 256, 0, stream>>>(cnt, rowptr, bsum, dinv, N);
  scan2_kernel<<<1, 128, 0, stream>>>(bsum, bsum2, rowptr, NB, N);
  scan3_kernel<<<NB, 256, 0, stream>>>(rowptr, bsum2, N);
  fill_kernel<<<e4blocks, 256, 0, stream>>>(cols, rows, rowptr, cnt, adj, E, N);

  int gblocks = (N + 127) / 128;
  int ablocks = (N + 15) / 16;
  // layer 1: xws1 = dinv ⊙ (x@W1) (bf16) ; h = relu(dinv⊙Σ + b1) -> bufH (bf16)
  gemm_mfma_kernel<0><<<gblocks, 256, 0, stream>>>(x, Wt1, dinv, bufXW, N);
  aggregate_kernel<1, 1><<<ablocks, 256, 0, stream>>>(
      (const uint4*)bufXW, rowptr, adj, dinv, b1, bufH, N);
  // layer 2: xws2 = dinv ⊙ (h@W2) (bf16) ; out = dinv⊙Σ + b2 -> d_out (fp32)
  gemm_mfma_kernel<1><<<gblocks, 256, 0, stream>>>(bufH, Wt2, dinv, bufXW, N);
  aggregate_kernel<0, 0><<<ablocks, 256, 0, stream>>>(
      (const uint4*)bufXW, rowptr, adj, dinv, b2, out, N);
}